// Round 3
// baseline (1151.038 us; speedup 1.0000x reference)
//
#include <hip/hip_runtime.h>
#include <math.h>

#define DEV static __device__ __forceinline__

typedef short bf16x8 __attribute__((ext_vector_type(8)));
typedef float f32x4 __attribute__((ext_vector_type(4)));
typedef unsigned short u16x4 __attribute__((ext_vector_type(4)));
typedef unsigned short u16x8 __attribute__((ext_vector_type(8)));
typedef unsigned short ushort_t;

constexpr int Bsz = 8, Ssz = 2048, Dsz = 1024;
constexpr long long SD = (long long)Ssz * Dsz;   // 2,097,152
constexpr long long SS = (long long)Ssz * Ssz;   // 4,194,304
constexpr int Mtot = Bsz * Ssz;                  // 16384

DEV float bf2f(ushort_t u) {
    unsigned int i = ((unsigned int)u) << 16;
    float f; __builtin_memcpy(&f, &i, 4); return f;
}
DEV ushort_t f2bf(float f) {  // RNE
    unsigned int i; __builtin_memcpy(&i, &f, 4);
    return (ushort_t)((i + 0x7fffu + ((i >> 16) & 1u)) >> 16);
}

DEV void gload16(const void* g, void* l) {
    __builtin_amdgcn_global_load_lds(
        (const __attribute__((address_space(1))) unsigned int*)g,
        (__attribute__((address_space(3))) unsigned int*)l,
        16, 0, 0);
}

// ---------------- weight transpose (+optional hi/lo split), 1024x1024 ----------------
__global__ __launch_bounds__(256)
void transpose_split_kernel(const float* __restrict__ W, ushort_t* __restrict__ Th,
                            ushort_t* __restrict__ Tl) {
    __shared__ float tile[32][33];
    const int bx = blockIdx.x * 32, by = blockIdx.y * 32;
    const int tx = threadIdx.x & 31, ty = threadIdx.x >> 5;  // 32 x 8
#pragma unroll
    for (int i = 0; i < 32; i += 8)
        tile[ty + i][tx] = W[(size_t)(by + ty + i) * 1024 + bx + tx];
    __syncthreads();
#pragma unroll
    for (int i = 0; i < 32; i += 8) {
        float v = tile[tx][ty + i];          // = W[by+tx][bx+ty+i]
        ushort_t h = f2bf(v);
        size_t idx = (size_t)(bx + ty + i) * 1024 + by + tx;  // T[n][k] = W[k][n]
        Th[idx] = h;
        if (Tl) Tl[idx] = f2bf(v - bf2f(h));
    }
}

// ---------------- row softmax: 2048 fp32 -> 2048 bf16, one block per row ----------------
__global__ __launch_bounds__(256)
void softmax_kernel(const float* __restrict__ S, ushort_t* __restrict__ P) {
    const size_t row = blockIdx.x;
    const float* s = S + row * 2048;
    ushort_t* p = P + row * 2048;
    const int t = threadIdx.x, lane = t & 63, wv = t >> 6;
    float x[8];
    f32x4 a = ((const f32x4*)(s + t * 8))[0];
    f32x4 b = ((const f32x4*)(s + t * 8))[1];
#pragma unroll
    for (int i = 0; i < 4; ++i) { x[i] = a[i]; x[i + 4] = b[i]; }
    float m = x[0];
#pragma unroll
    for (int i = 1; i < 8; ++i) m = fmaxf(m, x[i]);
    for (int o = 32; o; o >>= 1) m = fmaxf(m, __shfl_xor(m, o));
    __shared__ float red[4], red2[4];
    if (!lane) red[wv] = m;
    __syncthreads();
    m = fmaxf(fmaxf(red[0], red[1]), fmaxf(red[2], red[3]));
    float sum = 0.f;
#pragma unroll
    for (int i = 0; i < 8; ++i) { x[i] = __expf(x[i] - m); sum += x[i]; }
    for (int o = 32; o; o >>= 1) sum += __shfl_xor(sum, o);
    if (!lane) red2[wv] = sum;
    __syncthreads();
    sum = red2[0] + red2[1] + red2[2] + red2[3];
    float inv = 1.f / sum;
    u16x8 o8;
#pragma unroll
    for (int i = 0; i < 8; ++i) o8[i] = f2bf(x[i] * inv);
    *(u16x8*)(p + t * 8) = o8;
}

// ---------------- GEMM: C[M,N] = A[M,K] * B^T[N,K] (+bias), A-mode + epilogue variants
constexpr int AM_BF16 = 0;   // A is bf16 [M,K], staged via global_load_lds
constexpr int AM_F32 = 1;    // A is fp32 [M,K], reg-staged + converted to bf16 hi
constexpr int AM_F32S = 2;   // A is fp32, reg-staged + split to bf16 hi+lo
constexpr int AM_BF16S = 3;  // A given as bf16 hi/lo pair, both via global_load_lds

constexpr int EPI_F32 = 0;    // fp32 store (+bias if non-null)
constexpr int EPI_SPLIT = 1;  // +bias, store bf16 hi->C0, lo->C1
constexpr int EPI_BF16T = 2;  // +bias, store bf16 transposed vT[b][d][s]
constexpr int EPI_SIG = 3;    // +bias, sigmoid, bf16 store
constexpr int EPI_GATE = 4;   // multiply by gate (C1, bf16), bf16 store

template <int BK, int AMODE, bool BSPLIT, int EPI>
__global__ __launch_bounds__(256, 2)
void gemm_kernel(const void* __restrict__ A_, const void* __restrict__ Al_,
                 const ushort_t* __restrict__ Bh, const ushort_t* __restrict__ Bl,
                 const float* __restrict__ bias, void* __restrict__ C0,
                 void* __restrict__ C1, int M, int N, int K,
                 long long zA, long long zB, long long zC, long long zG) {
    constexpr bool AF32 = (AMODE == AM_F32 || AMODE == AM_F32S);
    constexpr int ABUF = (AMODE == AM_F32S || AMODE == AM_BF16S) ? 2 : 1;
    constexpr int BBUF = BSPLIT ? 2 : 1;
    constexpr bool SPLIT3 = (ABUF == 2) && BSPLIT;   // bf16x3: AhBh + AhBl + AlBh
    __shared__ ushort_t smem[2][ABUF + BBUF][128 * BK];

    const int z = blockIdx.z;
    const int tid = threadIdx.x, lane = tid & 63, wv = tid >> 6;
    const int m0 = blockIdx.y * 128, n0 = blockIdx.x * 128;

    const ushort_t* pBh = Bh + (size_t)z * zB;
    const ushort_t* pBl = nullptr;
    if constexpr (BSPLIT) pBl = Bl + (size_t)z * zB;

    // ---- staging geometry for bf16 global_load_lds paths
    constexpr int CPR = BK / 8;           // 16B chunks per row
    constexpr int RPW = 64 / CPR;         // rows per wave per pass
    constexpr int PASSES = 128 / (4 * RPW);
    const int srow = lane / CPR;
    const int scol = (lane % CPR) * 8;

    auto stageB = [&](int db, int kt) {
#pragma unroll
        for (int p = 0; p < PASSES; ++p) {
            int rg = p * (4 * RPW) + wv * RPW;
            int r = rg + srow;
            gload16(pBh + (size_t)(n0 + r) * K + kt + scol, &smem[db][ABUF][rg * BK]);
            if constexpr (BSPLIT)
                gload16(pBl + (size_t)(n0 + r) * K + kt + scol, &smem[db][ABUF + 1][rg * BK]);
        }
    };

    // ---- A staging
    const ushort_t* pAh = nullptr;
    const ushort_t* pAl = nullptr;
    const float* pAf = nullptr;
    if constexpr (AF32) {
        pAf = (const float*)A_ + (size_t)z * zA;
    } else {
        pAh = (const ushort_t*)A_ + (size_t)z * zA;
        if constexpr (AMODE == AM_BF16S) pAl = (const ushort_t*)Al_ + (size_t)z * zA;
    }

    auto stageAbf = [&](int db, int kt) {
#pragma unroll
        for (int p = 0; p < PASSES; ++p) {
            int rg = p * (4 * RPW) + wv * RPW;
            int r = rg + srow;
            gload16(pAh + (size_t)(m0 + r) * K + kt + scol, &smem[db][0][rg * BK]);
            if constexpr (AMODE == AM_BF16S)
                gload16(pAl + (size_t)(m0 + r) * K + kt + scol, &smem[db][1][rg * BK]);
        }
    };

    // fp32 A path: reg-stage (issue loads early), convert+ds_write late (T14)
    constexpr int FCH = BK / 4;             // 16B fp32 chunks per row
    constexpr int NCH = (128 * FCH) / 256;  // chunks per thread (BK32:4, BK64:8)
    f32x4 areg[NCH];
    auto loadA = [&](int kt) {
#pragma unroll
        for (int ch = 0; ch < NCH; ++ch) {
            int c = ch * 256 + tid, r = c / FCH, cc = c % FCH;
            areg[ch] = *(const f32x4*)(pAf + (size_t)(m0 + r) * K + kt + cc * 4);
        }
    };
    auto writeA = [&](int db) {
#pragma unroll
        for (int ch = 0; ch < NCH; ++ch) {
            int c = ch * 256 + tid, r = c / FCH, cc = c % FCH;
            u16x4 hv, lv;
#pragma unroll
            for (int j = 0; j < 4; ++j) {
                hv[j] = f2bf(areg[ch][j]);
                lv[j] = f2bf(areg[ch][j] - bf2f(hv[j]));
            }
            *(u16x4*)&smem[db][0][r * BK + cc * 4] = hv;
            if constexpr (AMODE == AM_F32S)
                *(u16x4*)&smem[db][1][r * BK + cc * 4] = lv;
        }
    };

    const int wr = wv >> 1, wc = wv & 1;  // 2x2 wave grid, 64x64 per wave
    const int fr = lane & 15;
    const int fq = lane >> 4;

    f32x4 acc[4][4];
#pragma unroll
    for (int i = 0; i < 4; ++i)
#pragma unroll
        for (int j = 0; j < 4; ++j) acc[i][j] = f32x4{0.f, 0.f, 0.f, 0.f};

    const int NT = K / BK;
    int db = 0;
    if constexpr (AF32) loadA(0);
    stageB(0, 0);
    if constexpr (AF32) writeA(0); else stageAbf(0, 0);
    __syncthreads();

    for (int t = 0; t < NT; ++t) {
        if (t + 1 < NT) {
            if constexpr (AF32) loadA((t + 1) * BK);   // loads first: their wait won't drain B
            stageB(db ^ 1, (t + 1) * BK);
            if constexpr (!AF32) stageAbf(db ^ 1, (t + 1) * BK);
        }
#pragma unroll
        for (int kk = 0; kk < BK / 32; ++kk) {
            bf16x8 a_h[4], b_h[4], a_l[4], b_l[4];
#pragma unroll
            for (int m = 0; m < 4; ++m) {
                int row = wr * 64 + m * 16 + fr;
                a_h[m] = *(const bf16x8*)&smem[db][0][row * BK + kk * 32 + fq * 8];
                if constexpr (SPLIT3)
                    a_l[m] = *(const bf16x8*)&smem[db][1][row * BK + kk * 32 + fq * 8];
            }
#pragma unroll
            for (int n = 0; n < 4; ++n) {
                int col = wc * 64 + n * 16 + fr;
                b_h[n] = *(const bf16x8*)&smem[db][ABUF][col * BK + kk * 32 + fq * 8];
                if constexpr (SPLIT3)
                    b_l[n] = *(const bf16x8*)&smem[db][ABUF + 1][col * BK + kk * 32 + fq * 8];
            }
#pragma unroll
            for (int m = 0; m < 4; ++m)
#pragma unroll
                for (int n = 0; n < 4; ++n) {
                    acc[m][n] = __builtin_amdgcn_mfma_f32_16x16x32_bf16(a_h[m], b_h[n], acc[m][n], 0, 0, 0);
                    if constexpr (SPLIT3) {
                        acc[m][n] = __builtin_amdgcn_mfma_f32_16x16x32_bf16(a_h[m], b_l[n], acc[m][n], 0, 0, 0);
                        acc[m][n] = __builtin_amdgcn_mfma_f32_16x16x32_bf16(a_l[m], b_h[n], acc[m][n], 0, 0, 0);
                    }
                }
        }
        if constexpr (AF32) { if (t + 1 < NT) writeA(db ^ 1); }
        __syncthreads();
        db ^= 1;
    }

    // epilogue: C frag mapping col=lane&15, row=(lane>>4)*4+i  [m89 verified]
#pragma unroll
    for (int n = 0; n < 4; ++n) {
        const int col = n0 + wc * 64 + n * 16 + fr;
        const float bv = bias ? bias[col] : 0.f;
#pragma unroll
        for (int m = 0; m < 4; ++m) {
            const int r0 = m0 + wr * 64 + m * 16 + fq * 4;
#pragma unroll
            for (int i = 0; i < 4; ++i) {
                const int row = r0 + i;
                const float val = acc[m][n][i] + bv;
                if constexpr (EPI == EPI_F32) {
                    ((float*)C0)[(size_t)z * zC + (size_t)row * N + col] = val;
                } else if constexpr (EPI == EPI_SPLIT) {
                    ushort_t h = f2bf(val);
                    ((ushort_t*)C0)[(size_t)row * N + col] = h;
                    ((ushort_t*)C1)[(size_t)row * N + col] = f2bf(val - bf2f(h));
                } else if constexpr (EPI == EPI_BF16T) {
                    const int bb = row >> 11, ss = row & 2047;  // S=2048
                    ((ushort_t*)C0)[(((size_t)(bb << 10) + col) << 11) + ss] = f2bf(val);
                } else if constexpr (EPI == EPI_SIG) {
                    ((ushort_t*)C0)[(size_t)row * N + col] = f2bf(1.f / (1.f + __expf(-val)));
                } else if constexpr (EPI == EPI_GATE) {
                    const float g = bf2f(((const ushort_t*)C1)[(size_t)z * zG + (size_t)row * N + col]);
                    ((ushort_t*)C0)[(size_t)z * zC + (size_t)row * N + col] = f2bf(val * g);
                }
            }
        }
    }
}

// ------------------------------- host launcher -------------------------------
extern "C" void kernel_launch(void* const* d_in, const int* in_sizes, int n_in,
                              void* d_out, int out_size, void* d_ws, size_t ws_size,
                              hipStream_t stream) {
    const float* queries = (const float*)d_in[0];
    const float* keys = (const float*)d_in[1];
    const float* values = (const float*)d_in[2];
    const float* Wq = (const float*)d_in[3]; const float* bq = (const float*)d_in[4];
    const float* Wk = (const float*)d_in[5]; const float* bk = (const float*)d_in[6];
    const float* Wv = (const float*)d_in[7]; const float* bv = (const float*)d_in[8];
    const float* Wg = (const float*)d_in[9]; const float* bg = (const float*)d_in[10];
    const float* Wo = (const float*)d_in[11]; const float* bo = (const float*)d_in[12];

    // batch-chunked workspace: C=2 needs 126 MiB, C=1 needs 86 MiB
    const int C = (ws_size >= 132120576UL) ? 2 : 1;

    char* ws = (char*)d_ws;
    size_t off = 0;
    auto walloc = [&](size_t bytes) { void* p = ws + off; off += bytes; return p; };
    ushort_t* gctx = (ushort_t*)walloc(33554432UL);                 // [16384,1024] bf16
    ushort_t* qH = (ushort_t*)walloc((size_t)C * 4194304UL);        // [C,2048,1024] bf16
    ushort_t* qL = (ushort_t*)walloc((size_t)C * 4194304UL);
    ushort_t* kH = (ushort_t*)walloc((size_t)C * 4194304UL);
    ushort_t* kL = (ushort_t*)walloc((size_t)C * 4194304UL);
    float* scores = (float*)walloc((size_t)C * 16777216UL);         // [C,2048,2048] fp32
    ushort_t* attn = (ushort_t*)walloc((size_t)C * 8388608UL);      // [C,2048,2048] bf16
    ushort_t* WqTh = (ushort_t*)walloc(2097152UL);
    ushort_t* WqTl = (ushort_t*)walloc(2097152UL);
    ushort_t* WkTh = (ushort_t*)walloc(2097152UL);
    ushort_t* WkTl = (ushort_t*)walloc(2097152UL);
    ushort_t* WvT = (ushort_t*)walloc(2097152UL);
    ushort_t* WgT = (ushort_t*)walloc(2097152UL);
    ushort_t* WoT = (ushort_t*)walloc(2097152UL);

    // gate and vT live in d_out (dead before the final out-GEMM overwrites it)
    ushort_t* gate = (ushort_t*)d_out;          // [16384,1024] bf16 = 32 MiB
    ushort_t* vT = gate + 16777216UL;           // [8,1024,2048] bf16 = 32 MiB

    dim3 tb(256), tg(32, 32);
    transpose_split_kernel<<<tg, tb, 0, stream>>>(Wq, WqTh, WqTl);
    transpose_split_kernel<<<tg, tb, 0, stream>>>(Wk, WkTh, WkTl);
    transpose_split_kernel<<<tg, tb, 0, stream>>>(Wv, WvT, nullptr);
    transpose_split_kernel<<<tg, tb, 0, stream>>>(Wg, WgT, nullptr);
    transpose_split_kernel<<<tg, tb, 0, stream>>>(Wo, WoT, nullptr);

    // v projection -> vT[b][d][s]  (A = fp32 values, in-kernel convert)
    gemm_kernel<64, AM_F32, false, EPI_BF16T><<<dim3(8, 128, 1), 256, 0, stream>>>(
        values, nullptr, WvT, nullptr, bv, vT, nullptr, Mtot, 1024, 1024, 0, 0, 0, 0);
    // gate = sigmoid(queries @ Wg + bg)
    gemm_kernel<64, AM_F32, false, EPI_SIG><<<dim3(8, 128, 1), 256, 0, stream>>>(
        queries, nullptr, WgT, nullptr, bg, gate, nullptr, Mtot, 1024, 1024, 0, 0, 0, 0);

    for (int b0 = 0; b0 < Bsz; b0 += C) {
        const int MC = C * Ssz;
        // q/k projections for this chunk: fp32 A split in-kernel, bf16x3 vs split W
        gemm_kernel<32, AM_F32S, true, EPI_SPLIT><<<dim3(8, MC / 128, 1), 256, 0, stream>>>(
            queries + (size_t)b0 * SD, nullptr, WqTh, WqTl, bq, qH, qL, MC, 1024, 1024, 0, 0, 0, 0);
        gemm_kernel<32, AM_F32S, true, EPI_SPLIT><<<dim3(8, MC / 128, 1), 256, 0, stream>>>(
            keys + (size_t)b0 * SD, nullptr, WkTh, WkTl, bk, kH, kL, MC, 1024, 1024, 0, 0, 0, 0);
        // scores[z] = q[z] @ k[z]^T  (bf16x3, fp32 out)
        gemm_kernel<32, AM_BF16S, true, EPI_F32><<<dim3(16, 16, C), 256, 0, stream>>>(
            qH, qL, kH, kL, nullptr, scores, nullptr, Ssz, Ssz, 1024, SD, SD, SS, 0);
        softmax_kernel<<<C * Ssz, 256, 0, stream>>>(scores, attn);
        // ctx[z] = attn[z] @ v[z]; gated; bf16 store into gctx rows of this chunk
        gemm_kernel<64, AM_BF16, false, EPI_GATE><<<dim3(8, 16, C), 256, 0, stream>>>(
            attn, nullptr, vT + (size_t)b0 * SD, nullptr, nullptr,
            gctx + (size_t)b0 * SD, gate + (size_t)b0 * SD, Ssz, 1024, Ssz, SS, SD, SD, SD);
    }

    // out = gctx @ Wo + bo (fp32) — overwrites all of d_out (gate/vT dead)
    gemm_kernel<64, AM_BF16, false, EPI_F32><<<dim3(8, 128, 1), 256, 0, stream>>>(
        gctx, nullptr, WoT, nullptr, bo, d_out, nullptr, Mtot, 1024, 1024, 0, 0, 0, 0);

    (void)in_sizes; (void)n_in; (void)out_size; (void)ws_size;
}